// Round 13
// baseline (122.677 us; speedup 1.0000x reference)
//
#include <hip/hip_runtime.h>

#define CIN   32
#define COUT  64
#define XG    256
#define ZG    256

// ---------------- Real kernel: proven round-2 atomic scatter ----------
__global__ __launch_bounds__(256) void tobev_real(
    const float* __restrict__ feats,
    const int*   __restrict__ coords,
    const float* __restrict__ kern,
    float* __restrict__ out,
    int n)
{
    const int wid  = blockIdx.x * 4 + (threadIdx.x >> 6);
    const int lane = threadIdx.x & 63;
    if (wid >= n) return;
    const int4 c = *reinterpret_cast<const int4*>(coords + (size_t)wid * 4);
    const int idx = c.y;
    const int lin = (c.w * XG + c.x) * ZG + c.z;
    const float f = feats[(size_t)wid * CIN + (lane & 31)];
    const float* __restrict__ w = kern + (size_t)idx * (CIN * COUT) + lane;
    float acc = 0.f;
    #pragma unroll
    for (int i = 0; i < CIN; ++i)
        acc = fmaf(__shfl(f, i, 64), w[(size_t)i * COUT], acc);
    unsafeAtomicAdd(&out[(size_t)lin * COUT + lane], acc);
}

// ---------------- Probe NA: same compute+weights, NO atomics ----------
// Stores into an 8 MiB ws window (coalesced). Measures weight/L2 side.
__global__ __launch_bounds__(256) void probe_na(
    const float* __restrict__ feats,
    const int*   __restrict__ coords,
    const float* __restrict__ kern,
    float* __restrict__ wsf,
    int n)
{
    const int wid  = blockIdx.x * 4 + (threadIdx.x >> 6);
    const int lane = threadIdx.x & 63;
    if (wid >= n) return;
    const int4 c = *reinterpret_cast<const int4*>(coords + (size_t)wid * 4);
    const int idx = c.y;
    const float f = feats[(size_t)wid * CIN + (lane & 31)];
    const float* __restrict__ w = kern + (size_t)idx * (CIN * COUT) + lane;
    float acc = 0.f;
    #pragma unroll
    for (int i = 0; i < CIN; ++i)
        acc = fmaf(__shfl(f, i, 64), w[(size_t)i * COUT], acc);
    wsf[((size_t)(wid & 32767) * COUT) + lane] = acc;      // 8 MiB wrap, no atomics
}

// ---------------- Probe NW: bin-0 weights (L1-hot), SAME atomics ------
// Adds exactly +/-0.0f so d_out is unchanged. Measures atomic RMW side.
__global__ __launch_bounds__(256) void probe_nw(
    const float* __restrict__ feats,
    const int*   __restrict__ coords,
    const float* __restrict__ kern,
    float* __restrict__ out,
    int n)
{
    const int wid  = blockIdx.x * 4 + (threadIdx.x >> 6);
    const int lane = threadIdx.x & 63;
    if (wid >= n) return;
    const int4 c = *reinterpret_cast<const int4*>(coords + (size_t)wid * 4);
    const int lin = (c.w * XG + c.x) * ZG + c.z;
    const float f = feats[(size_t)wid * CIN + (lane & 31)];
    const float* __restrict__ w = kern + lane;             // bin 0 for all -> L1-resident
    float acc = 0.f;
    #pragma unroll
    for (int i = 0; i < CIN; ++i)
        acc = fmaf(__shfl(f, i, 64), w[(size_t)i * COUT], acc);
    unsafeAtomicAdd(&out[(size_t)lin * COUT + lane], acc * 0.0f);  // +/-0: output-neutral
}

extern "C" void kernel_launch(void* const* d_in, const int* in_sizes, int n_in,
                              void* d_out, int out_size, void* d_ws, size_t ws_size,
                              hipStream_t stream) {
    const float* feats  = (const float*)d_in[0];
    const int*   coords = (const int*)d_in[1];
    const float* kern   = (const float*)d_in[2];
    float* out = (float*)d_out;
    float* wsf = (float*)d_ws;
    const int n = in_sizes[0] / CIN;                       // N = 100000

    hipMemsetAsync(d_out, 0, (size_t)out_size * sizeof(float), stream);

    const int blocks = (n + 3) / 4;
    hipLaunchKernelGGL(tobev_real, dim3(blocks), dim3(256), 0, stream,
                       feats, coords, kern, out, n);
    // Diagnostic probes (deterministic, output-neutral); rocprof reports
    // their individual durations -> weight-bound vs atomic-bound split.
    hipLaunchKernelGGL(probe_na, dim3(blocks), dim3(256), 0, stream,
                       feats, coords, kern, wsf, n);
    hipLaunchKernelGGL(probe_nw, dim3(blocks), dim3(256), 0, stream,
                       feats, coords, kern, out, n);
}

// Round 15
// 58.623 us; speedup vs baseline: 2.0926x; 2.0926x over previous
//
#include <hip/hip_runtime.h>

#define CIN   32
#define COUT  64
#define XG    256
#define ZG    256

// One wave = 64 points; in-wave bin dedup; quad weight layout (g-major).
//   lane l: g = l>>4 selects cin octet (rows 8g..8g+7)
//           q = l&15 selects cout quad (cols 4q..4q+3)
//   weights: 8 dwordx4 per distinct bin; wq[j] = w[8g+j][4q..4q+4)
//   feats:   2 float4 per point; fs[j] = f[8g+j]
//   butterfly xor16+xor32 sums the 4 cin octets; lane adds cout 4q+g.
// No LDS, no __syncthreads, no workspace: race surface == round-13 kernel.
__global__ __launch_bounds__(256) void tobev_dedup(
    const float* __restrict__ feats,
    const int*   __restrict__ coords,
    const float* __restrict__ kern,
    float* __restrict__ out,
    int n)
{
    const int wv   = threadIdx.x >> 6;
    const int lane = threadIdx.x & 63;
    const int wid  = blockIdx.x * 4 + wv;
    const int base = wid * 64;

    int m = n - base;                                // points this wave
    m = m < 0 ? 0 : (m > 64 ? 64 : m);
    if (m == 0) return;                              // wave-uniform

    const int g = lane >> 4;                         // cin octet 0..3
    const int q = lane & 15;                         // cout quad 0..15

    int idx_v = 0, lin_v = 0;
    if (lane < m) {                                  // 1 int4 instr / 64 pts
        const int4 c = *reinterpret_cast<const int4*>(coords + (size_t)(base + lane) * 4);
        idx_v = c.y;                                 // STRIDE == 1
        lin_v = (c.w * XG + c.x) * ZG + c.z;
    }

    unsigned long long done = (m >= 64) ? 0ull : (~0ull << m);

    while (done != ~0ull) {                          // one iter per distinct bin
        const int p0   = __ffsll((unsigned long long)~done) - 1;
        const int bidx = __shfl(idx_v, p0, 64);      // run's bin (wave-uniform)
        unsigned long long bm = __ballot(idx_v == bidx) & ~done;
        done |= bm;

        // bin weights: 8 dwordx4 (g-major quad layout)
        const float* __restrict__ wb = kern + (size_t)bidx * (CIN * COUT) + 512 * g + 4 * q;
        float4 wq[8];
        #pragma unroll
        for (int j = 0; j < 8; ++j)
            wq[j] = *reinterpret_cast<const float4*>(wb + 64 * j);   // w[8g+j][4q..)

        while (bm) {                                 // points of this bin
            const int p = __ffsll(bm) - 1;
            bm &= bm - 1;
            const int lin = __shfl(lin_v, p, 64);    // wave-uniform
            const int ps  = base + p;

            // feats octet for this lane: f[8g..8g+8) -- 2 broadcast float4s
            const float* __restrict__ fp = feats + (size_t)ps * CIN + 8 * g;
            const float4 fA = *reinterpret_cast<const float4*>(fp);
            const float4 fB = *reinterpret_cast<const float4*>(fp + 4);
            const float fs[8] = {fA.x, fA.y, fA.z, fA.w, fB.x, fB.y, fB.z, fB.w};

            float a0 = 0.f, a1 = 0.f, a2 = 0.f, a3 = 0.f;
            #pragma unroll
            for (int j = 0; j < 8; ++j) {            // static indexing after unroll
                const float fb = fs[j];
                a0 = fmaf(fb, wq[j].x, a0);
                a1 = fmaf(fb, wq[j].y, a1);
                a2 = fmaf(fb, wq[j].z, a2);
                a3 = fmaf(fb, wq[j].w, a3);
            }
            // sum the 4 cin octets (xor 16/32 preserves q, varies g)
            a0 += __shfl_xor(a0, 16, 64); a0 += __shfl_xor(a0, 32, 64);
            a1 += __shfl_xor(a1, 16, 64); a1 += __shfl_xor(a1, 32, 64);
            a2 += __shfl_xor(a2, 16, 64); a2 += __shfl_xor(a2, 32, 64);
            a3 += __shfl_xor(a3, 16, 64); a3 += __shfl_xor(a3, 32, 64);

            const float v = (g == 0) ? a0 : (g == 1) ? a1 : (g == 2) ? a2 : a3;
            unsafeAtomicAdd(&out[(size_t)lin * COUT + 4 * q + g], v);  // 1 instr/pt
        }
    }
}

extern "C" void kernel_launch(void* const* d_in, const int* in_sizes, int n_in,
                              void* d_out, int out_size, void* d_ws, size_t ws_size,
                              hipStream_t stream) {
    const float* feats  = (const float*)d_in[0];
    const int*   coords = (const int*)d_in[1];
    const float* kern   = (const float*)d_in[2];
    float* out = (float*)d_out;
    const int n = in_sizes[0] / CIN;                 // N = 100000

    hipMemsetAsync(d_out, 0, (size_t)out_size * sizeof(float), stream);

    const int nwaves = (n + 63) / 64;                // 1563
    const int blocks = (nwaves + 3) / 4;             // 391
    hipLaunchKernelGGL(tobev_dedup, dim3(blocks), dim3(256), 0, stream,
                       feats, coords, kern, out, n);
}

// Round 16
// 56.000 us; speedup vs baseline: 2.1906x; 1.0468x over previous
//
#include <hip/hip_runtime.h>

#define CIN   32
#define COUT  64
#define XG    256
#define ZG    256

// One wave = ONE point (r2's proven parallelism) + quad weight layout
// (r15's instruction efficiency). 12 VMEM instrs/point total:
//   1 int4 coords (wave-uniform) + 8 dwordx4 weights + 2 float4 feats
//   + 1 atomic.
//   lane l: g = l>>4 -> cin octet (rows 8g..8g+7)
//           q = l&15 -> cout quad (cols 4q..4q+3)
//   wq[j] = w[8g+j][4q..4q+4);  fs[j] = f[8g+j]
//   butterfly xor16+xor32 sums the 4 octets (q preserved);
//   lane adds cout 4q+g. No LDS, no syncthreads, no ballot, no ws.
__global__ __launch_bounds__(256) void tobev_quadp(
    const float* __restrict__ feats,
    const int*   __restrict__ coords,
    const float* __restrict__ kern,
    float* __restrict__ out,
    int n)
{
    const int wid  = blockIdx.x * 4 + (threadIdx.x >> 6);   // point id
    const int lane = threadIdx.x & 63;
    if (wid >= n) return;

    const int g = lane >> 4;                                // 0..3
    const int q = lane & 15;                                // 0..15

    const int4 c = *reinterpret_cast<const int4*>(coords + (size_t)wid * 4);
    const int idx = c.y;                                    // STRIDE == 1
    const int lin = (c.w * XG + c.x) * ZG + c.z;

    // 8 dwordx4 weight loads (whole 8 KiB bin across the wave)
    const float* __restrict__ wb = kern + (size_t)idx * (CIN * COUT) + 512 * g + 4 * q;
    float4 wq[8];
    #pragma unroll
    for (int j = 0; j < 8; ++j)
        wq[j] = *reinterpret_cast<const float4*>(wb + 64 * j);   // w[8g+j][4q..)

    // 2 float4 feats loads: f[8g..8g+8) (wave-uniform per octet group)
    const float* __restrict__ fp = feats + (size_t)wid * CIN + 8 * g;
    const float4 fA = *reinterpret_cast<const float4*>(fp);
    const float4 fB = *reinterpret_cast<const float4*>(fp + 4);
    const float fs[8] = {fA.x, fA.y, fA.z, fA.w, fB.x, fB.y, fB.z, fB.w};

    float a0 = 0.f, a1 = 0.f, a2 = 0.f, a3 = 0.f;
    #pragma unroll
    for (int j = 0; j < 8; ++j) {
        const float fb = fs[j];
        a0 = fmaf(fb, wq[j].x, a0);
        a1 = fmaf(fb, wq[j].y, a1);
        a2 = fmaf(fb, wq[j].z, a2);
        a3 = fmaf(fb, wq[j].w, a3);
    }
    // sum the 4 cin octets: xor16 flips g bit0, xor32 flips g bit1; q kept
    a0 += __shfl_xor(a0, 16, 64); a0 += __shfl_xor(a0, 32, 64);
    a1 += __shfl_xor(a1, 16, 64); a1 += __shfl_xor(a1, 32, 64);
    a2 += __shfl_xor(a2, 16, 64); a2 += __shfl_xor(a2, 32, 64);
    a3 += __shfl_xor(a3, 16, 64); a3 += __shfl_xor(a3, 32, 64);

    const float v = (g == 0) ? a0 : (g == 1) ? a1 : (g == 2) ? a2 : a3;
    unsafeAtomicAdd(&out[(size_t)lin * COUT + 4 * q + g], v);   // 1 instr/pt
}

extern "C" void kernel_launch(void* const* d_in, const int* in_sizes, int n_in,
                              void* d_out, int out_size, void* d_ws, size_t ws_size,
                              hipStream_t stream) {
    const float* feats  = (const float*)d_in[0];
    const int*   coords = (const int*)d_in[1];
    const float* kern   = (const float*)d_in[2];
    float* out = (float*)d_out;
    const int n = in_sizes[0] / CIN;                        // N = 100000

    hipMemsetAsync(d_out, 0, (size_t)out_size * sizeof(float), stream);

    const int blocks = (n + 3) / 4;                         // 4 points per block
    hipLaunchKernelGGL(tobev_quadp, dim3(blocks), dim3(256), 0, stream,
                       feats, coords, kern, out, n);
}